// Round 3
// baseline (211.417 us; speedup 1.0000x reference)
//
#include <hip/hip_runtime.h>

#define NN 4096
#define FIN 256
#define FOUT 64
#define NH 4

using f32x4 = __attribute__((ext_vector_type(4))) float;
using s16x8 = __attribute__((ext_vector_type(8))) short;
typedef unsigned long long u64;

__device__ __forceinline__ unsigned short f32_to_bf16_rne(float f) {
    unsigned b = __float_as_uint(f);
    b += 0x7FFFu + ((b >> 16) & 1u);
    return (unsigned short)(b >> 16);
}

// Kernel A: Wh[h] = x @ W[h] via bf16 MFMA -> WhT bf16 [H][FOUT][NN]; s1,s2 (pre-scaled log2e)
__global__ __launch_bounds__(256) void k_wh(
    const float* __restrict__ x, const float* __restrict__ W,
    const float* __restrict__ a, short* __restrict__ WhT,
    float* __restrict__ s1, float* __restrict__ s2)
{
    __shared__ unsigned short xs[64 * 256];   // bf16 x-tile, XOR-swizzled (16B granule), 32 KB
    __shared__ unsigned short wt[64 * 256];   // bf16 W^T [o][f], XOR-swizzled, 32 KB
    const int nb = blockIdx.x, h = blockIdx.y, t = threadIdx.x;
    const int n0 = nb * 64;
    {
        const float4* xg = reinterpret_cast<const float4*>(x + (size_t)n0 * FIN);
        for (int k = t; k < 64 * FIN / 4; k += 256) {
            float4 v = xg[k];
            int row = k >> 6, fq = k & 63;
            u64 pk = (u64)f32_to_bf16_rne(v.x) | ((u64)f32_to_bf16_rne(v.y) << 16)
                   | ((u64)f32_to_bf16_rne(v.z) << 32) | ((u64)f32_to_bf16_rne(v.w) << 48);
            int byte = (row * 512 + fq * 8) ^ ((row & 7) << 4);
            *(u64*)((char*)xs + byte) = pk;
        }
        const float* Wg = W + (size_t)h * FIN * FOUT;
        for (int k = t; k < FIN * FOUT; k += 256) {
            int f = k >> 6, o = k & 63;
            unsigned short wv = f32_to_bf16_rne(Wg[k]);
            int byte = (o * 512 + f * 2) ^ ((o & 7) << 4);
            *(unsigned short*)((char*)wt + byte) = wv;
        }
    }
    __syncthreads();
    const int lane = t & 63, wv_ = t >> 6;
    const int rowA = lane & 15;
    const int kq = (lane >> 4) * 8;
    const int i0 = wv_ * 16;               // wave's 16-row block within 64-row tile
    f32x4 acc[4];
    #pragma unroll
    for (int c = 0; c < 4; ++c) acc[c] = (f32x4){0.f, 0.f, 0.f, 0.f};
    const int arow = i0 + rowA;
    #pragma unroll
    for (int kb = 0; kb < FIN; kb += 32) {
        int ab = (arow * 512 + (kb + kq) * 2) ^ ((arow & 7) << 4);
        s16x8 af = *(const s16x8*)((char*)xs + ab);
        #pragma unroll
        for (int c = 0; c < 4; ++c) {
            int col = c * 16 + rowA;
            int bb = (col * 512 + (kb + kq) * 2) ^ ((col & 7) << 4);
            s16x8 bf = *(const s16x8*)((char*)wt + bb);
            acc[c] = __builtin_amdgcn_mfma_f32_16x16x32_bf16(af, bf, acc[c], 0, 0, 0);
        }
    }
    // D layout: col = lane&15 (within c-tile), row = (lane>>4)*4 + q
    const int q0 = (lane >> 4) * 4;
    const float L2E = 1.4426950408889634f;
    float v1acc[4] = {0.f, 0.f, 0.f, 0.f}, v2acc[4] = {0.f, 0.f, 0.f, 0.f};
    #pragma unroll
    for (int c = 0; c < 4; ++c) {
        int col = c * 16 + rowA;
        float a1v = a[h * (2 * FOUT) + col];
        float a2v = a[h * (2 * FOUT) + FOUT + col];
        short* wp = WhT + ((size_t)(h * FOUT + col)) * NN + n0 + i0 + q0;
        alignas(8) unsigned short tmp[4];
        #pragma unroll
        for (int q = 0; q < 4; ++q) {
            float v = acc[c][q];
            tmp[q] = f32_to_bf16_rne(v);
            v1acc[q] = fmaf(v, a1v, v1acc[q]);
            v2acc[q] = fmaf(v, a2v, v2acc[q]);
        }
        __builtin_memcpy(wp, tmp, 8);
    }
    #pragma unroll
    for (int q = 0; q < 4; ++q) {
        float v1 = v1acc[q] * L2E, v2 = v2acc[q] * L2E;
        #pragma unroll
        for (int d = 1; d < 16; d <<= 1) {
            v1 += __shfl_xor(v1, d, 64);
            v2 += __shfl_xor(v2, d, 64);
        }
        if (rowA == 0) {
            int n = n0 + i0 + q0 + q;
            s1[h * NN + n] = v1;
            s2[h * NN + n] = v2;
        }
    }
}

// Kernel A2: pack adj into bitmask, packed[jw*NN + i] bit j%64
__global__ __launch_bounds__(256) void k_pack(const int* __restrict__ adj,
                                              u64* __restrict__ packed)
{
    const int t = threadIdx.x;
    const int lane = t & 63;
    const int row = blockIdx.x * 4 + (t >> 6);
    const int* ap = adj + (size_t)row * NN + lane;
    u64* pp = packed + row;
    #pragma unroll 4
    for (int jw = 0; jw < 64; ++jw) {
        int av = ap[jw * 64];
        u64 m = __ballot(av != 0);
        if (lane == 0) pp[(size_t)jw * NN] = m;
    }
}

// Kernel B: per-head global max of s2
__global__ __launch_bounds__(256) void k_s2max(const float* __restrict__ s2,
                                               float* __restrict__ s2m)
{
    const int h = blockIdx.x, t = threadIdx.x;
    __shared__ float red[256];
    float m = -1e30f;
    for (int j = t; j < NN; j += 256) m = fmaxf(m, s2[h * NN + j]);
    red[t] = m;
    __syncthreads();
    for (int st = 128; st > 0; st >>= 1) {
        if (t < st) red[t] = fmaxf(red[t], red[t + st]);
        __syncthreads();
    }
    if (t == 0) s2m[h] = red[0];
}

// Kernel C: fused masked-softmax + PV. Block = 4 waves (one per head), 16 rows.
__global__ __launch_bounds__(256, 8) void k_attn(
    const u64* __restrict__ packed, const short* __restrict__ WhT,
    const float* __restrict__ s1, const float* __restrict__ s2,
    const float* __restrict__ s2m, int nsplit,
    float* __restrict__ ws_acc, float* __restrict__ ws_l)
{
    __shared__ unsigned short p_lds[NH][16 * 64];
    const int t = threadIdx.x;
    const int lane = t & 63;
    const int h = t >> 6;
    const int ib = blockIdx.x;
    const int s = blockIdx.y;
    const int i0 = ib * 16;

    float s1m1[16], s1m2[16], lsum[16];
    const float s2mv = s2m[h];
    const float* s1p = s1 + h * NN + i0;
    #pragma unroll
    for (int r = 0; r < 16; ++r) {
        float v = s1p[r];
        float tt = v + s2mv;
        float M = fmaxf(tt, 0.2f * tt);     // upper bound on row logits
        s1m1[r] = v - M;                    // e = max(s1+s2-M, 0.2(s1+s2)-M)
        s1m2[r] = 0.2f * v - M;
        lsum[r] = 0.f;
    }
    f32x4 acc[4];
    #pragma unroll
    for (int c = 0; c < 4; ++c) acc[c] = (f32x4){0.f, 0.f, 0.f, 0.f};

    const float* s2p = s2 + h * NN;
    const int row16 = lane & 15;
    const int kbase = (lane >> 4) * 8;
    char* pw = (char*)&p_lds[h][0];
    const int wr_off = lane * 2;
    const int rd0 = row16 * 128 + ((kbase * 2) ^ ((row16 & 7) << 4));
    const int rd1 = row16 * 128 + (((kbase + 32) * 2) ^ ((row16 & 7) << 4));
    const short* wbase = WhT + (size_t)h * FOUT * NN;
    const short* bp0 = wbase + (size_t)(0 * 16 + row16) * NN + kbase;
    const short* bp1 = wbase + (size_t)(1 * 16 + row16) * NN + kbase;
    const short* bp2 = wbase + (size_t)(2 * 16 + row16) * NN + kbase;
    const short* bp3 = wbase + (size_t)(3 * 16 + row16) * NN + kbase;

    for (int jb = s * 64; jb < NN; jb += nsplit * 64) {
        s16x8 b00 = *(const s16x8*)(bp0 + jb);
        s16x8 b01 = *(const s16x8*)(bp0 + jb + 32);
        s16x8 b10 = *(const s16x8*)(bp1 + jb);
        s16x8 b11 = *(const s16x8*)(bp1 + jb + 32);
        s16x8 b20 = *(const s16x8*)(bp2 + jb);
        s16x8 b21 = *(const s16x8*)(bp2 + jb + 32);
        s16x8 b30 = *(const s16x8*)(bp3 + jb);
        s16x8 b31 = *(const s16x8*)(bp3 + jb + 32);
        const u64* mrow = packed + (size_t)(jb >> 6) * NN + i0;   // wave-uniform -> s_load
        float s2v = s2p[jb + lane];
        float s2v2 = 0.2f * s2v;
        #pragma unroll
        for (int r = 0; r < 16; ++r) {
            u64 mr = mrow[r];
            float t1 = s1m1[r] + s2v;
            float t2 = s1m2[r] + s2v2;
            float e = fmaxf(t1, t2);
            float p = __builtin_amdgcn_exp2f(e);
            p = ((mr >> lane) & 1ull) ? p : 0.f;
            unsigned short pb = f32_to_bf16_rne(p);
            lsum[r] += __uint_as_float((unsigned)pb << 16);
            *(unsigned short*)(pw + (r * 128 + (wr_off ^ ((r & 7) << 4)))) = pb;
        }
        s16x8 a0 = *(const s16x8*)(pw + rd0);
        s16x8 a1 = *(const s16x8*)(pw + rd1);
        acc[0] = __builtin_amdgcn_mfma_f32_16x16x32_bf16(a0, b00, acc[0], 0, 0, 0);
        acc[0] = __builtin_amdgcn_mfma_f32_16x16x32_bf16(a1, b01, acc[0], 0, 0, 0);
        acc[1] = __builtin_amdgcn_mfma_f32_16x16x32_bf16(a0, b10, acc[1], 0, 0, 0);
        acc[1] = __builtin_amdgcn_mfma_f32_16x16x32_bf16(a1, b11, acc[1], 0, 0, 0);
        acc[2] = __builtin_amdgcn_mfma_f32_16x16x32_bf16(a0, b20, acc[2], 0, 0, 0);
        acc[2] = __builtin_amdgcn_mfma_f32_16x16x32_bf16(a1, b21, acc[2], 0, 0, 0);
        acc[3] = __builtin_amdgcn_mfma_f32_16x16x32_bf16(a0, b30, acc[3], 0, 0, 0);
        acc[3] = __builtin_amdgcn_mfma_f32_16x16x32_bf16(a1, b31, acc[3], 0, 0, 0);
    }

    const int widx = ((ib * nsplit + s) * NH + h) * 16;
    #pragma unroll
    for (int r = 0; r < 16; ++r) {
        float v = lsum[r];
        #pragma unroll
        for (int d = 1; d < 64; d <<= 1) v += __shfl_xor(v, d, 64);
        if (lane == 0) ws_l[widx + r] = v;
    }
    float* ap = ws_acc + (size_t)widx * 64;
    #pragma unroll
    for (int c = 0; c < 4; ++c) {
        #pragma unroll
        for (int q = 0; q < 4; ++q) {
            int row = (lane >> 4) * 4 + q;
            int col = c * 16 + row16;
            ap[row * 64 + col] = acc[c][q];
        }
    }
}

// Kernel D: merge nsplit j-splits, divide by l, write out[n][h*64+o]
__global__ __launch_bounds__(256) void k_merge(
    const float* __restrict__ ws_acc, const float* __restrict__ ws_l,
    int nsplit, float* __restrict__ out)
{
    const int idx = blockIdx.x * 256 + threadIdx.x;
    const int o = idx & 63;
    const int h = (idx >> 6) & 3;
    const int n = idx >> 8;
    const int ib = n >> 4, r = n & 15;
    float l = 0.f, v = 0.f;
    for (int s = 0; s < nsplit; ++s) {
        const int w = ((ib * nsplit + s) * NH + h) * 16 + r;
        l += ws_l[w];
        v += ws_acc[(size_t)w * 64 + o];
    }
    out[idx] = v / l;
}

extern "C" void kernel_launch(void* const* d_in, const int* in_sizes, int n_in,
                              void* d_out, int out_size, void* d_ws, size_t ws_size,
                              hipStream_t stream) {
    (void)in_sizes; (void)n_in; (void)out_size;
    const float* x  = (const float*)d_in[0];
    const int*  adj = (const int*)d_in[1];
    const float* W  = (const float*)d_in[2];
    const float* a  = (const float*)d_in[3];
    float* out = (float*)d_out;
    char* ws = (char*)d_ws;

    size_t off = 0;
    short* WhT   = (short*)(ws + off); off += (size_t)NH * FOUT * NN * 2;   // 2 MB
    float* s1    = (float*)(ws + off); off += (size_t)NH * NN * 4;          // 64 KB
    float* s2    = (float*)(ws + off); off += (size_t)NH * NN * 4;          // 64 KB
    float* s2m   = (float*)(ws + off); off += 256;
    u64*   packed= (u64*)  (ws + off); off += (size_t)(NN / 64) * NN * 8;   // 2 MB

    int nsplit = 8;                       // 8 splits -> 32 waves/CU; needs ~38 MB ws
    size_t need8 = off + (size_t)256 * 8 * NH * 16 * (64 + 1) * 4;
    if (ws_size < need8) nsplit = 4;
    float* ws_l   = (float*)(ws + off); off += (size_t)256 * nsplit * NH * 16 * 4;
    float* ws_acc = (float*)(ws + off);

    k_wh<<<dim3(64, 4), 256, 0, stream>>>(x, W, a, WhT, s1, s2);
    k_pack<<<1024, 256, 0, stream>>>(adj, packed);
    k_s2max<<<4, 256, 0, stream>>>(s2, s2m);
    k_attn<<<dim3(256, nsplit), 256, 0, stream>>>(packed, WhT, s1, s2, s2m, nsplit, ws_acc, ws_l);
    k_merge<<<4096, 256, 0, stream>>>(ws_acc, ws_l, nsplit, out);
}

// Round 4
// 119.052 us; speedup vs baseline: 1.7758x; 1.7758x over previous
//
#include <hip/hip_runtime.h>

#define NN 4096
#define FIN 256
#define FOUT 64
#define NH 4

using f32x4 = __attribute__((ext_vector_type(4))) float;
using s16x8 = __attribute__((ext_vector_type(8))) short;
typedef unsigned long long u64;

__device__ __forceinline__ unsigned short f32_to_bf16_rne(float f) {
    unsigned b = __float_as_uint(f);
    b += 0x7FFFu + ((b >> 16) & 1u);
    return (unsigned short)(b >> 16);
}

// Kernel A: Wh[h] = x @ W[h] via bf16 MFMA -> WhT bf16 [H][FOUT][NN]; s1,s2 (pre-scaled log2e)
__global__ __launch_bounds__(256) void k_wh(
    const float* __restrict__ x, const float* __restrict__ W,
    const float* __restrict__ a, short* __restrict__ WhT,
    float* __restrict__ s1, float* __restrict__ s2)
{
    __shared__ unsigned short xs[64 * 256];   // bf16 x-tile, XOR-swizzled (16B granule), 32 KB
    __shared__ unsigned short wt[64 * 256];   // bf16 W^T [o][f], XOR-swizzled, 32 KB
    const int nb = blockIdx.x, h = blockIdx.y, t = threadIdx.x;
    const int n0 = nb * 64;
    {
        const float4* xg = reinterpret_cast<const float4*>(x + (size_t)n0 * FIN);
        for (int k = t; k < 64 * FIN / 4; k += 256) {
            float4 v = xg[k];
            int row = k >> 6, fq = k & 63;
            u64 pk = (u64)f32_to_bf16_rne(v.x) | ((u64)f32_to_bf16_rne(v.y) << 16)
                   | ((u64)f32_to_bf16_rne(v.z) << 32) | ((u64)f32_to_bf16_rne(v.w) << 48);
            int byte = (row * 512 + fq * 8) ^ ((row & 7) << 4);
            *(u64*)((char*)xs + byte) = pk;
        }
        const float* Wg = W + (size_t)h * FIN * FOUT;
        for (int k = t; k < FIN * FOUT; k += 256) {
            int f = k >> 6, o = k & 63;
            unsigned short wv = f32_to_bf16_rne(Wg[k]);
            int byte = (o * 512 + f * 2) ^ ((o & 7) << 4);
            *(unsigned short*)((char*)wt + byte) = wv;
        }
    }
    __syncthreads();
    const int lane = t & 63, wv_ = t >> 6;
    const int rowA = lane & 15;
    const int kq = (lane >> 4) * 8;
    const int i0 = wv_ * 16;
    f32x4 acc[4];
    #pragma unroll
    for (int c = 0; c < 4; ++c) acc[c] = (f32x4){0.f, 0.f, 0.f, 0.f};
    const int arow = i0 + rowA;
    #pragma unroll
    for (int kb = 0; kb < FIN; kb += 32) {
        int ab = (arow * 512 + (kb + kq) * 2) ^ ((arow & 7) << 4);
        s16x8 af = *(const s16x8*)((char*)xs + ab);
        #pragma unroll
        for (int c = 0; c < 4; ++c) {
            int col = c * 16 + rowA;
            int bb = (col * 512 + (kb + kq) * 2) ^ ((col & 7) << 4);
            s16x8 bf = *(const s16x8*)((char*)wt + bb);
            acc[c] = __builtin_amdgcn_mfma_f32_16x16x32_bf16(af, bf, acc[c], 0, 0, 0);
        }
    }
    const int q0 = (lane >> 4) * 4;
    const float L2E = 1.4426950408889634f;
    float v1acc[4] = {0.f, 0.f, 0.f, 0.f}, v2acc[4] = {0.f, 0.f, 0.f, 0.f};
    #pragma unroll
    for (int c = 0; c < 4; ++c) {
        int col = c * 16 + rowA;
        float a1v = a[h * (2 * FOUT) + col];
        float a2v = a[h * (2 * FOUT) + FOUT + col];
        short* wp = WhT + ((size_t)(h * FOUT + col)) * NN + n0 + i0 + q0;
        alignas(8) unsigned short tmp[4];
        #pragma unroll
        for (int q = 0; q < 4; ++q) {
            float v = acc[c][q];
            tmp[q] = f32_to_bf16_rne(v);
            v1acc[q] = fmaf(v, a1v, v1acc[q]);
            v2acc[q] = fmaf(v, a2v, v2acc[q]);
        }
        __builtin_memcpy(wp, tmp, 8);
    }
    #pragma unroll
    for (int q = 0; q < 4; ++q) {
        float v1 = v1acc[q] * L2E, v2 = v2acc[q] * L2E;
        #pragma unroll
        for (int d = 1; d < 16; d <<= 1) {
            v1 += __shfl_xor(v1, d, 64);
            v2 += __shfl_xor(v2, d, 64);
        }
        if (rowA == 0) {
            int n = n0 + i0 + q0 + q;
            s1[h * NN + n] = v1;
            s2[h * NN + n] = v2;
        }
    }
}

// Kernel A2: pack adj into bitmask, packed[jw*NN + i] bit j%64
__global__ __launch_bounds__(256) void k_pack(const int* __restrict__ adj,
                                              u64* __restrict__ packed)
{
    const int t = threadIdx.x;
    const int lane = t & 63;
    const int row = blockIdx.x * 4 + (t >> 6);
    const int* ap = adj + (size_t)row * NN + lane;
    u64* pp = packed + row;
    #pragma unroll 4
    for (int jw = 0; jw < 64; ++jw) {
        int av = ap[jw * 64];
        u64 m = __ballot(av != 0);
        if (lane == 0) pp[(size_t)jw * NN] = m;
    }
}

// Kernel B: per-row constants c1 = s1 - M, c2 = 0.2*s1 - M  (M = LeakyReLU(s1 + max_j s2))
// Each block recomputes its head's s2-max (4096 reads, L2-hit) then does 256 elementwise.
__global__ __launch_bounds__(256) void k_prep(
    const float* __restrict__ s1, const float* __restrict__ s2,
    float* __restrict__ c1g, float* __restrict__ c2g)
{
    const int t = threadIdx.x;
    const int idx = blockIdx.x * 256 + t;      // over NH*NN
    const int h = idx >> 12;
    __shared__ float red[256];
    const float* s2p = s2 + (h << 12);
    float m = -1e30f;
    for (int j = t; j < NN; j += 256) m = fmaxf(m, s2p[j]);
    red[t] = m;
    __syncthreads();
    for (int st = 128; st > 0; st >>= 1) {
        if (t < st) red[t] = fmaxf(red[t], red[t + st]);
        __syncthreads();
    }
    float s2mv = red[0];
    float v = s1[idx];
    float tt = v + s2mv;
    float M = fmaxf(tt, 0.2f * tt);
    c1g[idx] = v - M;
    c2g[idx] = fmaf(0.2f, v, -M);
}

// Kernel C: fused masked-softmax + PV. Block = 4 waves (one per head), 16 rows.
// NOTE: (256,8) launch bounds caused catastrophic spill (R3: 254MB scratch writes).
// Occupancy comes from low actual VGPR use instead: row constants in SGPRs,
// l-sum via all-ones MFMA column, mask via SGPR-pair v_cndmask.
__global__ __launch_bounds__(256, 4) void k_attn(
    const u64* __restrict__ packed, const short* __restrict__ WhT,
    const float* __restrict__ c1g, const float* __restrict__ c2g,
    const float* __restrict__ s2, int nsplit,
    float* __restrict__ ws_acc, float* __restrict__ ws_l)
{
    __shared__ unsigned short p_lds[NH][16 * 64];
    const int t = threadIdx.x;
    const int lane = t & 63;
    const int h = __builtin_amdgcn_readfirstlane(t >> 6);   // wave-uniform -> scalar addressing
    const int ib = blockIdx.x;
    const int s = blockIdx.y;
    const int i0 = ib * 16;

    // row constants -> uniform loads -> SGPRs
    const float* c1p = c1g + h * NN + i0;
    const float* c2p = c2g + h * NN + i0;
    float c1[16], c2[16];
    #pragma unroll
    for (int r = 0; r < 16; ++r) { c1[r] = c1p[r]; c2[r] = c2p[r]; }

    f32x4 acc[4], acc_l;
    #pragma unroll
    for (int c = 0; c < 4; ++c) acc[c] = (f32x4){0.f, 0.f, 0.f, 0.f};
    acc_l = (f32x4){0.f, 0.f, 0.f, 0.f};
    s16x8 ones;
    #pragma unroll
    for (int i = 0; i < 8; ++i) ones[i] = (short)0x3F80;   // bf16 1.0

    const float* s2p = s2 + h * NN;
    const int row16 = lane & 15;
    const int kbase = (lane >> 4) * 8;
    char* pw = (char*)&p_lds[h][0];
    const int wr_off = lane * 2;
    const int rd0 = row16 * 128 + ((kbase * 2) ^ ((row16 & 7) << 4));
    const int rd1 = row16 * 128 + (((kbase + 32) * 2) ^ ((row16 & 7) << 4));
    const short* bbase = WhT + (size_t)h * FOUT * NN + (size_t)row16 * NN + kbase;

    for (int jb = s * 64; jb < NN; jb += nsplit * 64) {
        const short* bp = bbase + jb;
        s16x8 b00 = *(const s16x8*)(bp);
        s16x8 b01 = *(const s16x8*)(bp + 32);
        s16x8 b10 = *(const s16x8*)(bp + 16 * NN);
        s16x8 b11 = *(const s16x8*)(bp + 16 * NN + 32);
        s16x8 b20 = *(const s16x8*)(bp + 32 * NN);
        s16x8 b21 = *(const s16x8*)(bp + 32 * NN + 32);
        s16x8 b30 = *(const s16x8*)(bp + 48 * NN);
        s16x8 b31 = *(const s16x8*)(bp + 48 * NN + 32);
        const u64* mrow = packed + (size_t)(jb >> 6) * NN + i0;   // uniform -> s_load
        float s2v = s2p[jb + lane];
        float s2v2 = 0.2f * s2v;
        #pragma unroll
        for (int r = 0; r < 16; ++r) {
            u64 mr = mrow[r];
            float e = fmaxf(c1[r] + s2v, c2[r] + s2v2);
            float p = __builtin_amdgcn_exp2f(e);
            asm("v_cndmask_b32 %0, 0, %1, %2" : "=v"(p) : "v"(p), "s"(mr));
            unsigned short pb = f32_to_bf16_rne(p);
            *(unsigned short*)(pw + (r * 128 + (wr_off ^ ((r & 7) << 4)))) = pb;
        }
        // in-wave DS ordering: reads-after-writes within the same wave
        s16x8 a0 = *(const s16x8*)(pw + rd0);
        s16x8 a1 = *(const s16x8*)(pw + rd1);
        acc_l  = __builtin_amdgcn_mfma_f32_16x16x32_bf16(a0, ones, acc_l, 0, 0, 0);
        acc_l  = __builtin_amdgcn_mfma_f32_16x16x32_bf16(a1, ones, acc_l, 0, 0, 0);
        acc[0] = __builtin_amdgcn_mfma_f32_16x16x32_bf16(a0, b00, acc[0], 0, 0, 0);
        acc[0] = __builtin_amdgcn_mfma_f32_16x16x32_bf16(a1, b01, acc[0], 0, 0, 0);
        acc[1] = __builtin_amdgcn_mfma_f32_16x16x32_bf16(a0, b10, acc[1], 0, 0, 0);
        acc[1] = __builtin_amdgcn_mfma_f32_16x16x32_bf16(a1, b11, acc[1], 0, 0, 0);
        acc[2] = __builtin_amdgcn_mfma_f32_16x16x32_bf16(a0, b20, acc[2], 0, 0, 0);
        acc[2] = __builtin_amdgcn_mfma_f32_16x16x32_bf16(a1, b21, acc[2], 0, 0, 0);
        acc[3] = __builtin_amdgcn_mfma_f32_16x16x32_bf16(a0, b30, acc[3], 0, 0, 0);
        acc[3] = __builtin_amdgcn_mfma_f32_16x16x32_bf16(a1, b31, acc[3], 0, 0, 0);
    }

    const int widx = ((ib * nsplit + s) * NH + h) * 16;
    // acc_l: every column holds the row-sum; rows (lane>>4)*4+q. Lanes with row16==0 cover all 16.
    if (row16 == 0) {
        #pragma unroll
        for (int q = 0; q < 4; ++q) ws_l[widx + (lane >> 4) * 4 + q] = acc_l[q];
    }
    float* ap = ws_acc + (size_t)widx * 64;
    #pragma unroll
    for (int c = 0; c < 4; ++c) {
        #pragma unroll
        for (int q = 0; q < 4; ++q) {
            int row = (lane >> 4) * 4 + q;
            int col = c * 16 + row16;
            ap[row * 64 + col] = acc[c][q];
        }
    }
}

// Kernel D: merge nsplit j-splits, divide by l, write out[n][h*64+o]
__global__ __launch_bounds__(256) void k_merge(
    const float* __restrict__ ws_acc, const float* __restrict__ ws_l,
    int nsplit, float* __restrict__ out)
{
    const int idx = blockIdx.x * 256 + threadIdx.x;
    const int o = idx & 63;
    const int h = (idx >> 6) & 3;
    const int n = idx >> 8;
    const int ib = n >> 4, r = n & 15;
    float l = 0.f, v = 0.f;
    for (int s = 0; s < nsplit; ++s) {
        const int w = ((ib * nsplit + s) * NH + h) * 16 + r;
        l += ws_l[w];
        v += ws_acc[(size_t)w * 64 + o];
    }
    out[idx] = v / l;
}

extern "C" void kernel_launch(void* const* d_in, const int* in_sizes, int n_in,
                              void* d_out, int out_size, void* d_ws, size_t ws_size,
                              hipStream_t stream) {
    (void)in_sizes; (void)n_in; (void)out_size;
    const float* x  = (const float*)d_in[0];
    const int*  adj = (const int*)d_in[1];
    const float* W  = (const float*)d_in[2];
    const float* a  = (const float*)d_in[3];
    float* out = (float*)d_out;
    char* ws = (char*)d_ws;

    size_t off = 0;
    short* WhT   = (short*)(ws + off); off += (size_t)NH * FOUT * NN * 2;   // 2 MB
    float* s1    = (float*)(ws + off); off += (size_t)NH * NN * 4;          // 64 KB
    float* s2    = (float*)(ws + off); off += (size_t)NH * NN * 4;          // 64 KB
    float* c1g   = (float*)(ws + off); off += (size_t)NH * NN * 4;          // 64 KB
    float* c2g   = (float*)(ws + off); off += (size_t)NH * NN * 4;          // 64 KB
    u64*   packed= (u64*)  (ws + off); off += (size_t)(NN / 64) * NN * 8;   // 2 MB

    int nsplit = 8;
    size_t need8 = off + (size_t)256 * 8 * NH * 16 * (64 + 1) * 4;
    if (ws_size < need8) nsplit = 4;
    float* ws_l   = (float*)(ws + off); off += (size_t)256 * nsplit * NH * 16 * 4;
    float* ws_acc = (float*)(ws + off);

    k_wh<<<dim3(64, 4), 256, 0, stream>>>(x, W, a, WhT, s1, s2);
    k_pack<<<1024, 256, 0, stream>>>(adj, packed);
    k_prep<<<NH * NN / 256, 256, 0, stream>>>(s1, s2, c1g, c2g);
    k_attn<<<dim3(256, nsplit), 256, 0, stream>>>(packed, WhT, c1g, c2g, s2, nsplit, ws_acc, ws_l);
    k_merge<<<4096, 256, 0, stream>>>(ws_acc, ws_l, nsplit, out);
}

// Round 5
// 109.034 us; speedup vs baseline: 1.9390x; 1.0919x over previous
//
#include <hip/hip_runtime.h>

#define NN 4096
#define FIN 256
#define FOUT 64
#define NH 4
#define NSPLIT 4

using f32x4 = __attribute__((ext_vector_type(4))) float;
using s16x8 = __attribute__((ext_vector_type(8))) short;
typedef unsigned long long u64;

__device__ __forceinline__ unsigned short f32_to_bf16_rne(float f) {
    unsigned b = __float_as_uint(f);
    b += 0x7FFFu + ((b >> 16) & 1u);
    return (unsigned short)(b >> 16);
}

// Kernel A: Wh[h] = x @ W[h] via bf16 MFMA -> WhT bf16 [H][FOUT][NN]; s1,s2 (pre-scaled log2e)
__global__ __launch_bounds__(256) void k_wh(
    const float* __restrict__ x, const float* __restrict__ W,
    const float* __restrict__ a, short* __restrict__ WhT,
    float* __restrict__ s1, float* __restrict__ s2)
{
    __shared__ unsigned short xs[64 * 256];   // bf16 x-tile, XOR-swizzled (16B granule), 32 KB
    __shared__ unsigned short wt[64 * 256];   // bf16 W^T [o][f], XOR-swizzled, 32 KB
    const int nb = blockIdx.x, h = blockIdx.y, t = threadIdx.x;
    const int n0 = nb * 64;
    {
        const float4* xg = reinterpret_cast<const float4*>(x + (size_t)n0 * FIN);
        for (int k = t; k < 64 * FIN / 4; k += 256) {
            float4 v = xg[k];
            int row = k >> 6, fq = k & 63;
            u64 pk = (u64)f32_to_bf16_rne(v.x) | ((u64)f32_to_bf16_rne(v.y) << 16)
                   | ((u64)f32_to_bf16_rne(v.z) << 32) | ((u64)f32_to_bf16_rne(v.w) << 48);
            int byte = (row * 512 + fq * 8) ^ ((row & 7) << 4);
            *(u64*)((char*)xs + byte) = pk;
        }
        const float* Wg = W + (size_t)h * FIN * FOUT;
        for (int k = t; k < FIN * FOUT; k += 256) {
            int f = k >> 6, o = k & 63;
            unsigned short wv = f32_to_bf16_rne(Wg[k]);
            int byte = (o * 512 + f * 2) ^ ((o & 7) << 4);
            *(unsigned short*)((char*)wt + byte) = wv;
        }
    }
    __syncthreads();
    const int lane = t & 63, wv_ = t >> 6;
    const int rowA = lane & 15;
    const int kq = (lane >> 4) * 8;
    const int i0 = wv_ * 16;
    f32x4 acc[4];
    #pragma unroll
    for (int c = 0; c < 4; ++c) acc[c] = (f32x4){0.f, 0.f, 0.f, 0.f};
    const int arow = i0 + rowA;
    #pragma unroll
    for (int kb = 0; kb < FIN; kb += 32) {
        int ab = (arow * 512 + (kb + kq) * 2) ^ ((arow & 7) << 4);
        s16x8 af = *(const s16x8*)((char*)xs + ab);
        #pragma unroll
        for (int c = 0; c < 4; ++c) {
            int col = c * 16 + rowA;
            int bb = (col * 512 + (kb + kq) * 2) ^ ((col & 7) << 4);
            s16x8 bf = *(const s16x8*)((char*)wt + bb);
            acc[c] = __builtin_amdgcn_mfma_f32_16x16x32_bf16(af, bf, acc[c], 0, 0, 0);
        }
    }
    const int q0 = (lane >> 4) * 4;
    const float L2E = 1.4426950408889634f;
    float v1acc[4] = {0.f, 0.f, 0.f, 0.f}, v2acc[4] = {0.f, 0.f, 0.f, 0.f};
    #pragma unroll
    for (int c = 0; c < 4; ++c) {
        int col = c * 16 + rowA;
        float a1v = a[h * (2 * FOUT) + col];
        float a2v = a[h * (2 * FOUT) + FOUT + col];
        short* wp = WhT + ((size_t)(h * FOUT + col)) * NN + n0 + i0 + q0;
        alignas(8) unsigned short tmp[4];
        #pragma unroll
        for (int q = 0; q < 4; ++q) {
            float v = acc[c][q];
            tmp[q] = f32_to_bf16_rne(v);
            v1acc[q] = fmaf(v, a1v, v1acc[q]);
            v2acc[q] = fmaf(v, a2v, v2acc[q]);
        }
        __builtin_memcpy(wp, tmp, 8);
    }
    #pragma unroll
    for (int q = 0; q < 4; ++q) {
        float v1 = v1acc[q] * L2E, v2 = v2acc[q] * L2E;
        #pragma unroll
        for (int d = 1; d < 16; d <<= 1) {
            v1 += __shfl_xor(v1, d, 64);
            v2 += __shfl_xor(v2, d, 64);
        }
        if (rowA == 0) {
            int n = n0 + i0 + q0 + q;
            s1[h * NN + n] = v1;
            s2[h * NN + n] = v2;
        }
    }
}

// Kernel A2: pack adj into bitmask, packed[jw*NN + i] bit j%64
__global__ __launch_bounds__(256) void k_pack(const int* __restrict__ adj,
                                              u64* __restrict__ packed)
{
    const int t = threadIdx.x;
    const int lane = t & 63;
    const int row = blockIdx.x * 4 + (t >> 6);
    const int* ap = adj + (size_t)row * NN + lane;
    u64* pp = packed + row;
    #pragma unroll 4
    for (int jw = 0; jw < 64; ++jw) {
        int av = ap[jw * 64];
        u64 m = __ballot(av != 0);
        if (lane == 0) pp[(size_t)jw * NN] = m;
    }
}

// Kernel B: per-row constants c1 = s1 - M, c2 = 0.2*s1 - M  (M = LeakyReLU(s1 + max_j s2))
__global__ __launch_bounds__(256) void k_prep(
    const float* __restrict__ s1, const float* __restrict__ s2,
    float* __restrict__ c1g, float* __restrict__ c2g)
{
    const int t = threadIdx.x;
    const int idx = blockIdx.x * 256 + t;      // over NH*NN
    const int h = idx >> 12;
    __shared__ float red[256];
    const float* s2p = s2 + (h << 12);
    float m = -1e30f;
    for (int j = t; j < NN; j += 256) m = fmaxf(m, s2p[j]);
    red[t] = m;
    __syncthreads();
    for (int st = 128; st > 0; st >>= 1) {
        if (t < st) red[t] = fmaxf(red[t], red[t + st]);
        __syncthreads();
    }
    float s2mv = red[0];
    float v = s1[idx];
    float tt = v + s2mv;
    float M = fmaxf(tt, 0.2f * tt);
    c1g[idx] = v - M;
    c2g[idx] = fmaf(0.2f, v, -M);
}

// Kernel C: fused masked-softmax + PV. Block = 4 waves (one per head), 16 rows.
// 1-deep pipeline: s2 + mask words for iter k+1 prefetched during iter k, so the
// score phase enters stall-free and its issue time covers the B-frag L2 latency.
__global__ __launch_bounds__(256, 4) void k_attn(
    const u64* __restrict__ packed, const short* __restrict__ WhT,
    const float* __restrict__ c1g, const float* __restrict__ c2g,
    const float* __restrict__ s2,
    float* __restrict__ ws_acc, float* __restrict__ ws_l)
{
    __shared__ unsigned short p_lds[NH][16 * 64];
    const int t = threadIdx.x;
    const int lane = t & 63;
    const int h = __builtin_amdgcn_readfirstlane(t >> 6);
    const int ib = blockIdx.x;
    const int s = blockIdx.y;
    const int i0 = ib * 16;

    const float* c1p = c1g + h * NN + i0;
    const float* c2p = c2g + h * NN + i0;
    float c1[16], c2[16];
    #pragma unroll
    for (int r = 0; r < 16; ++r) { c1[r] = c1p[r]; c2[r] = c2p[r]; }

    f32x4 acc[4], acc_l;
    #pragma unroll
    for (int c = 0; c < 4; ++c) acc[c] = (f32x4){0.f, 0.f, 0.f, 0.f};
    acc_l = (f32x4){0.f, 0.f, 0.f, 0.f};
    s16x8 ones;
    #pragma unroll
    for (int i = 0; i < 8; ++i) ones[i] = (short)0x3F80;   // bf16 1.0

    const float* s2p = s2 + h * NN;
    const int row16 = lane & 15;
    const int kbase = (lane >> 4) * 8;
    char* pw = (char*)&p_lds[h][0];
    const int wr_off = lane * 2;
    const int rd0 = row16 * 128 + ((kbase * 2) ^ ((row16 & 7) << 4));
    const int rd1 = row16 * 128 + (((kbase + 32) * 2) ^ ((row16 & 7) << 4));
    const short* bbase = WhT + (size_t)h * FOUT * NN + (size_t)row16 * NN + kbase;

    auto body = [&](int jb, u64 (&cm)[16], float s2v, u64 (&nm)[16], float& s2n) {
        // B-frag loads for THIS iter (latency covered by the score phase below)
        const short* bp = bbase + jb;
        s16x8 b00 = *(const s16x8*)(bp);
        s16x8 b01 = *(const s16x8*)(bp + 32);
        s16x8 b10 = *(const s16x8*)(bp + 16 * NN);
        s16x8 b11 = *(const s16x8*)(bp + 16 * NN + 32);
        s16x8 b20 = *(const s16x8*)(bp + 32 * NN);
        s16x8 b21 = *(const s16x8*)(bp + 32 * NN + 32);
        s16x8 b30 = *(const s16x8*)(bp + 48 * NN);
        s16x8 b31 = *(const s16x8*)(bp + 48 * NN + 32);
        // prefetch NEXT iter's s2 + masks (clamped to a safe in-bounds addr on last iter)
        int jn = jb + NSPLIT * 64;
        int jpf = (jn < NN) ? jn : (s * 64);
        s2n = s2p[jpf + lane];
        const u64* mrow = packed + (size_t)(jpf >> 6) * NN + i0;   // wave-uniform
        #pragma unroll
        for (int r = 0; r < 16; ++r) nm[r] = mrow[r];
        // score phase: stall-free (s2v, cm already resident)
        float s2v2 = 0.2f * s2v;
        #pragma unroll
        for (int rp = 0; rp < 8; ++rp) {
            const int r0 = 2 * rp, r1 = 2 * rp + 1;
            float e0 = fmaxf(c1[r0] + s2v, c2[r0] + s2v2);
            float e1 = fmaxf(c1[r1] + s2v, c2[r1] + s2v2);
            float p0 = __builtin_amdgcn_exp2f(e0);
            float p1 = __builtin_amdgcn_exp2f(e1);
            asm("v_cndmask_b32 %0, 0, %1, %2" : "=v"(p0) : "v"(p0), "s"(cm[r0]));
            asm("v_cndmask_b32 %0, 0, %1, %2" : "=v"(p1) : "v"(p1), "s"(cm[r1]));
            unsigned pk;
            asm("v_cvt_pk_bf16_f32 %0, %1, %2" : "=v"(pk) : "v"(p0), "v"(p1));
            *(unsigned short*)(pw + (r0 * 128 + (wr_off ^ ((r0 & 7) << 4)))) = (unsigned short)pk;
            *(unsigned short*)(pw + (r1 * 128 + (wr_off ^ ((r1 & 7) << 4)))) = (unsigned short)(pk >> 16);
        }
        // in-wave DS ordering: reads-after-writes within the same wave
        s16x8 a0 = *(const s16x8*)(pw + rd0);
        s16x8 a1 = *(const s16x8*)(pw + rd1);
        acc_l  = __builtin_amdgcn_mfma_f32_16x16x32_bf16(a0, ones, acc_l, 0, 0, 0);
        acc_l  = __builtin_amdgcn_mfma_f32_16x16x32_bf16(a1, ones, acc_l, 0, 0, 0);
        acc[0] = __builtin_amdgcn_mfma_f32_16x16x32_bf16(a0, b00, acc[0], 0, 0, 0);
        acc[0] = __builtin_amdgcn_mfma_f32_16x16x32_bf16(a1, b01, acc[0], 0, 0, 0);
        acc[1] = __builtin_amdgcn_mfma_f32_16x16x32_bf16(a0, b10, acc[1], 0, 0, 0);
        acc[1] = __builtin_amdgcn_mfma_f32_16x16x32_bf16(a1, b11, acc[1], 0, 0, 0);
        acc[2] = __builtin_amdgcn_mfma_f32_16x16x32_bf16(a0, b20, acc[2], 0, 0, 0);
        acc[2] = __builtin_amdgcn_mfma_f32_16x16x32_bf16(a1, b21, acc[2], 0, 0, 0);
        acc[3] = __builtin_amdgcn_mfma_f32_16x16x32_bf16(a0, b30, acc[3], 0, 0, 0);
        acc[3] = __builtin_amdgcn_mfma_f32_16x16x32_bf16(a1, b31, acc[3], 0, 0, 0);
    };

    // prologue: load iter-0 s2 + masks
    u64 m0[16], m1[16];
    float sv0, sv1;
    int jb = s * 64;
    {
        sv0 = s2p[jb + lane];
        const u64* mrow = packed + (size_t)(jb >> 6) * NN + i0;
        #pragma unroll
        for (int r = 0; r < 16; ++r) m0[r] = mrow[r];
    }
    #pragma unroll 1
    for (int it = 0; it < NN / (NSPLIT * 64) / 2; ++it) {
        body(jb, m0, sv0, m1, sv1);
        body(jb + NSPLIT * 64, m1, sv1, m0, sv0);
        jb += 2 * NSPLIT * 64;
    }

    const int widx = ((ib * NSPLIT + s) * NH + h) * 16;
    if (row16 == 0) {
        #pragma unroll
        for (int q = 0; q < 4; ++q) ws_l[widx + (lane >> 4) * 4 + q] = acc_l[q];
    }
    float* ap = ws_acc + (size_t)widx * 64;
    #pragma unroll
    for (int c = 0; c < 4; ++c) {
        #pragma unroll
        for (int q = 0; q < 4; ++q) {
            int row = (lane >> 4) * 4 + q;
            int col = c * 16 + row16;
            ap[row * 64 + col] = acc[c][q];
        }
    }
}

// Kernel D: merge NSPLIT j-splits, divide by l, write out[n][h*64+o]
__global__ __launch_bounds__(256) void k_merge(
    const float* __restrict__ ws_acc, const float* __restrict__ ws_l,
    float* __restrict__ out)
{
    const int idx = blockIdx.x * 256 + threadIdx.x;
    const int o = idx & 63;
    const int h = (idx >> 6) & 3;
    const int n = idx >> 8;
    const int ib = n >> 4, r = n & 15;
    float l = 0.f, v = 0.f;
    #pragma unroll
    for (int s = 0; s < NSPLIT; ++s) {
        const int w = ((ib * NSPLIT + s) * NH + h) * 16 + r;
        l += ws_l[w];
        v += ws_acc[(size_t)w * 64 + o];
    }
    out[idx] = v / l;
}

extern "C" void kernel_launch(void* const* d_in, const int* in_sizes, int n_in,
                              void* d_out, int out_size, void* d_ws, size_t ws_size,
                              hipStream_t stream) {
    (void)in_sizes; (void)n_in; (void)out_size; (void)ws_size;
    const float* x  = (const float*)d_in[0];
    const int*  adj = (const int*)d_in[1];
    const float* W  = (const float*)d_in[2];
    const float* a  = (const float*)d_in[3];
    float* out = (float*)d_out;
    char* ws = (char*)d_ws;

    size_t off = 0;
    short* WhT   = (short*)(ws + off); off += (size_t)NH * FOUT * NN * 2;   // 2 MB
    float* s1    = (float*)(ws + off); off += (size_t)NH * NN * 4;          // 64 KB
    float* s2    = (float*)(ws + off); off += (size_t)NH * NN * 4;          // 64 KB
    float* c1g   = (float*)(ws + off); off += (size_t)NH * NN * 4;          // 64 KB
    float* c2g   = (float*)(ws + off); off += (size_t)NH * NN * 4;          // 64 KB
    u64*   packed= (u64*)  (ws + off); off += (size_t)(NN / 64) * NN * 8;   // 2 MB
    float* ws_l  = (float*)(ws + off); off += (size_t)256 * NSPLIT * NH * 16 * 4;  // 256 KB
    float* ws_acc= (float*)(ws + off);                                      // 16.8 MB

    k_wh<<<dim3(64, 4), 256, 0, stream>>>(x, W, a, WhT, s1, s2);
    k_pack<<<1024, 256, 0, stream>>>(adj, packed);
    k_prep<<<NH * NN / 256, 256, 0, stream>>>(s1, s2, c1g, c2g);
    k_attn<<<dim3(256, NSPLIT), 256, 0, stream>>>(packed, WhT, c1g, c2g, s2, ws_acc, ws_l);
    k_merge<<<4096, 256, 0, stream>>>(ws_acc, ws_l, out);
}